// Round 12
// baseline (484.844 us; speedup 1.0000x reference)
//
#include <hip/hip_runtime.h>

#define LOG2E 1.4426950408889634f

typedef __attribute__((ext_vector_type(8))) short short8;
typedef __attribute__((ext_vector_type(4))) float f32x4;
using u32 = unsigned int;
using u16 = unsigned short;
using u64 = unsigned long long;

// ---------------------------------------------------------------------------
// Kernel 0: FUSED pack + k1f (one launch; pack is HBM-bound, k1f compute-
// bound -> they overlap inside one grid instead of serializing on the stream).
// blocks < 2048 : pack adj -> transposed bitmask (block 0 also zeroes cnt).
// blocks >= 2048: k1f = x @ W via bf16 MFMA. Self-contained: W staged to a
//   64 KB XOR-swizzled LDS tile (B ds_reads 2-way conflict = free), in-WG
//   K-split, red[] REUSES the wtl LDS after the K-loop (union; extra barrier).
// LDS 64 KB -> 2 blocks/CU; pack at 16 waves/CU still has enough ILP
// (16 waves x 4 x 256 B = 16 KB in flight > 9.2 KB needed at HBM latency).
// ---------------------------------------------------------------------------
__global__ __launch_bounds__(512) void k0(const int* __restrict__ adj,
                                          u32* __restrict__ mask_t,
                                          const float* __restrict__ x,
                                          const float* __restrict__ W,
                                          const float* __restrict__ a,
                                          u16* __restrict__ h_t,
                                          float* __restrict__ s1p,
                                          float* __restrict__ s2p,
                                          u32* __restrict__ cnt) {
    __shared__ u16 wtl[64 * 512];          // 64 KB; becomes red[] after K-loop
    const int tid = threadIdx.x;

    if (blockIdx.x < 2048) {               // ---------------- pack ----------------
        if (blockIdx.x == 0 && tid < 256) cnt[tid] = 0;   // fixup counters for k2
        const int wid = (blockIdx.x * 512 + tid) >> 6;
        const int lane = tid & 63;
        for (int t = wid; t < 65536; t += 16384) {        // task = (row, 4-chunk grp)
            const int r = t >> 4, c4 = t & 15;
            const int* base = adj + (size_t)r * 4096 + c4 * 256 + lane;
            int v0 = __builtin_nontemporal_load(base);
            int v1 = __builtin_nontemporal_load(base + 64);
            int v2 = __builtin_nontemporal_load(base + 128);
            int v3 = __builtin_nontemporal_load(base + 192);
            u64 b0 = __ballot(v0 > 0);
            u64 b1 = __ballot(v1 > 0);
            u64 b2 = __ballot(v2 > 0);
            u64 b3 = __ballot(v3 > 0);
            if (lane < 8) {
                u64 bv = (lane & 4) ? ((lane & 2) ? b3 : b2) : ((lane & 2) ? b1 : b0);
                u32 w = (u32)(bv >> ((lane & 1) << 5));
                mask_t[(size_t)(c4 * 8 + lane) * 4096 + r] = w;
            }
        }
        return;
    }
    // ---------------- k1f ----------------
    const int bx = blockIdx.x - 2048;      // 256 blocks: rt = bx&63, b = bx>>6
    const int rt = bx & 63, b = bx >> 6;
    {   // stage W (512x64 fp32) -> wtl[n][k] bf16, 16B-chunk XOR swizzle (n&7)
        const int kk = tid >> 4, n4 = (tid & 15) << 2;
#pragma unroll
        for (int it = 0; it < 16; it++) {
            int k = kk + it * 32;
            float4 w4 = *(const float4*)(W + (size_t)k * 64 + n4);
            const float* wf = (const float*)&w4;
            int kc = k >> 3, ko = k & 7;
#pragma unroll
            for (int i = 0; i < 4; i++) {
                int n = n4 + i;
                u32 v = __float_as_uint(wf[i]) + 0x8000u;       // round-half-up
                wtl[n * 512 + ((kc ^ (n & 7)) << 3) + ko] = (u16)(v >> 16);
            }
        }
    }
    __syncthreads();                       // wtl ready

    const int wave = tid >> 6, lane = tid & 63;
    const int g = wave & 3, kz = wave >> 2;
    const int m = lane & 15, quad = lane >> 4;
    const int row = rt * 64 + g * 16 + m;
    const float* xb = x + ((size_t)b * 4096 + row) * 512 + kz * 256 + quad * 8;

    f32x4 acc[4];
#pragma unroll
    for (int ot = 0; ot < 4; ot++) acc[ot] = (f32x4){0.f, 0.f, 0.f, 0.f};

    float4 ax[2][2];
#pragma unroll
    for (int s = 0; s < 2; s++) {          // preload A k-steps 0,1
        ax[s][0] = *(const float4*)(xb + s * 32);
        ax[s][1] = *(const float4*)(xb + s * 32 + 4);
    }
#pragma unroll
    for (int s = 0; s < 8; s++) {          // K=256 in 8 steps of 32
        const int cur = s & 1;
        union { u32 u[4]; short8 v; } af;
        const float* a0 = (const float*)&ax[cur][0];
#pragma unroll
        for (int p = 0; p < 4; p++) {      // round-half-up bf16 pack (lo=k even)
            u32 lo = __float_as_uint(a0[2 * p]) + 0x8000u;
            u32 hi = __float_as_uint(a0[2 * p + 1]) + 0x8000u;
            af.u[p] = __builtin_amdgcn_perm(hi, lo, 0x07060302u);
        }
#pragma unroll
        for (int ot = 0; ot < 4; ot++) {   // B direct from LDS (2-way = free)
            const int n = ot * 16 + m;
            const int chunk = kz * 32 + s * 4 + quad;
            short8 bv = *(const short8*)(wtl + n * 512 + ((chunk ^ (n & 7)) << 3));
            acc[ot] = __builtin_amdgcn_mfma_f32_16x16x32_bf16(af.v, bv, acc[ot], 0, 0, 0);
        }
        if (s + 2 < 8) {                   // A prefetch after consumption
            ax[cur][0] = *(const float4*)(xb + (s + 2) * 32);
            ax[cur][1] = *(const float4*)(xb + (s + 2) * 32 + 4);
        }
    }
    __syncthreads();                       // all wtl reads done -> reuse as red
    float* red = (float*)wtl;              // [4][16][64] fp32 = 16 KB
    if (kz) {
#pragma unroll
        for (int ot = 0; ot < 4; ot++)
#pragma unroll
            for (int r = 0; r < 4; r++)
                red[(g * 16 + quad * 4 + r) * 64 + ot * 16 + m] = acc[ot][r];
    }
    __syncthreads();
    if (kz) return;
#pragma unroll
    for (int ot = 0; ot < 4; ot++)
#pragma unroll
        for (int r = 0; r < 4; r++)
            acc[ot][r] += red[(g * 16 + quad * 4 + r) * 64 + ot * 16 + m];

    // epilogue: s1/s2 (pre-scaled by log2e) via shuffle reduce
    float a1v[4], a2v[4];
#pragma unroll
    for (int ot = 0; ot < 4; ot++) {
        a1v[ot] = a[ot * 16 + m];
        a2v[ot] = a[64 + ot * 16 + m];
    }
    float s1r[4], s2r[4];
#pragma unroll
    for (int r = 0; r < 4; r++) {
        s1r[r] = 0.f; s2r[r] = 0.f;
#pragma unroll
        for (int ot = 0; ot < 4; ot++) {
            s1r[r] = fmaf(acc[ot][r], a1v[ot], s1r[r]);
            s2r[r] = fmaf(acc[ot][r], a2v[ot], s2r[r]);
        }
    }
#pragma unroll
    for (int d = 1; d < 16; d <<= 1) {
#pragma unroll
        for (int r = 0; r < 4; r++) {
            s1r[r] += __shfl_xor(s1r[r], d);
            s2r[r] += __shfl_xor(s2r[r], d);
        }
    }
    if (m == 0) {
#pragma unroll
        for (int r = 0; r < 4; r++) {
            int rr = rt * 64 + g * 16 + quad * 4 + r;
            s1p[b * 4096 + rr] = s1r[r] * LOG2E;
            s2p[b * 4096 + rr] = s2r[r] * LOG2E;
        }
    }
    // h^T bf16 (round-half-up)
#pragma unroll
    for (int ot = 0; ot < 4; ot++) {
        u32 b0 = __float_as_uint(acc[ot][0]) + 0x8000u;
        u32 b1 = __float_as_uint(acc[ot][1]) + 0x8000u;
        u32 b2 = __float_as_uint(acc[ot][2]) + 0x8000u;
        u32 b3 = __float_as_uint(acc[ot][3]) + 0x8000u;
        uint2 u;
        u.x = (b0 >> 16) | (b1 & 0xffff0000u);
        u.y = (b2 >> 16) | (b3 & 0xffff0000u);
        *(uint2*)(h_t + ((size_t)(b * 64 + ot * 16 + m)) * 4096
                  + rt * 64 + g * 16 + quad * 4) = u;
    }
}

// ---------------------------------------------------------------------------
// Kernel 2: fused masked-softmax GEMM (r11 WIN body) + stream-K-style FIXUP
// absorbing k3: each WG stores its bf16 partial, fences, bumps a per-(b,rb)
// device-scope counter; the LAST of the S segment-WGs re-fences, reads all S
// partials (L2-hot), normalizes, applies elu, writes out. Kills k3's launch
// and its cold 16 MB re-read.
// ---------------------------------------------------------------------------
template <int NSTEP>
__global__ __launch_bounds__(256, 8) void k2_attn(const u16* __restrict__ h_t,
                                                  const u32* __restrict__ mask_t,
                                                  const float* __restrict__ s1p,
                                                  const float* __restrict__ s2p,
                                                  u16* __restrict__ part,
                                                  float* __restrict__ lp,
                                                  float* __restrict__ out,
                                                  u32* __restrict__ cnt) {
    constexpr int JSEG = NSTEP * 32;
    constexpr int S = 128 / NSTEP;         // j-split count
    constexpr int T = NSTEP / 2;           // 64-j tiles
    __shared__ u16 hB[2][64 * 64];         // double buffer, xor-swizzled
    __shared__ float s2l[JSEG];
    __shared__ u32 lastf;
    const int b = blockIdx.y, seg = blockIdx.z, rb = blockIdx.x;
    const int tid = threadIdx.x, wave = tid >> 6, lane = tid & 63;
    const int m = lane & 15, quad = lane >> 4;
    const int row = rb * 64 + wave * 16 + m;
    const int jstart = seg * JSEG;
    const float t1 = s1p[b * 4096 + row];
    const u16* hsrc = h_t + (size_t)b * 64 * 4096 + jstart;
    const u32* mrow = mask_t + (size_t)(jstart >> 5) * 4096 + row;

    for (int t = tid; t < (JSEG >> 2); t += 256)
        ((float4*)s2l)[t] = ((const float4*)(s2p + b * 4096 + jstart))[t];

    f32x4 acc[4], accd;
#pragma unroll
    for (int ot = 0; ot < 4; ot++) acc[ot] = (f32x4){0.f, 0.f, 0.f, 0.f};
    accd = (f32x4){0.f, 0.f, 0.f, 0.f};

    u32 mw[4];
#pragma unroll
    for (int s = 0; s < 4; s++) mw[s] = mrow[(size_t)s * 4096];
    union { u32 u[4]; short8 v; } ones;
#pragma unroll
    for (int p = 0; p < 4; p++) ones.u[p] = 0x3F803F80u;   // bf16 1.0 pairs

    const int cj = tid & 7;                // 16B chunk column (8 j's)
    const int ow = tid >> 3;               // rows ow, ow+32
    uint4 pf[2];
    pf[0] = *(const uint4*)(hsrc + (size_t)ow * 4096 + (cj << 3));
    pf[1] = *(const uint4*)(hsrc + (size_t)(ow + 32) * 4096 + (cj << 3));
    *(uint4*)(hB[0] + (size_t)ow * 64 + ((cj ^ (ow & 7)) << 3)) = pf[0];
    *(uint4*)(hB[0] + (size_t)(ow + 32) * 64 + ((cj ^ ((ow + 32) & 7)) << 3)) = pf[1];
    __syncthreads();                       // tile 0 + s2l ready

    for (int jt = 0; jt < T; jt++) {
        const int cb = jt & 1;
        if (jt + 1 < T) {                  // global prefetch of next 64-j tile
            pf[0] = *(const uint4*)(hsrc + (size_t)ow * 4096 + (jt + 1) * 64 + (cj << 3));
            pf[1] = *(const uint4*)(hsrc + (size_t)(ow + 32) * 4096 + (jt + 1) * 64 + (cj << 3));
        }
#pragma unroll
        for (int ks = 0; ks < 2; ks++) {
            const int s = jt * 2 + ks;
            // consume BEFORE the distance-4 prefetch overwrites the slot
            const u32 mws = mw[s & 3] >> (quad * 8);
            if (s + 4 < NSTEP) mw[(s + 4) & 3] = mrow[(size_t)(s + 4) * 4096];

            const float4 sa = *(const float4*)&s2l[s * 32 + quad * 8];
            const float4 sb = *(const float4*)&s2l[s * 32 + quad * 8 + 4];
            const float sv[8] = {sa.x, sa.y, sa.z, sa.w, sb.x, sb.y, sb.z, sb.w};
            union { u32 u[4]; short8 v; } af;
#pragma unroll
            for (int p = 0; p < 4; p++) {
                float t0 = t1 + sv[2 * p];
                float u0 = fmaxf(t0, 0.2f * t0);                     // leaky-relu (log2 dom)
                float w0 = __builtin_amdgcn_exp2f(u0);
                u32 m0 = (u32)(((int)(mws << (31 - 2 * p))) >> 31);  // bit -> all-ones/0
                u32 w0u = __float_as_uint(w0) & m0;                  // masked -> +0.0
                float t2 = t1 + sv[2 * p + 1];
                float u2 = fmaxf(t2, 0.2f * t2);
                float w1 = __builtin_amdgcn_exp2f(u2);
                u32 m1 = (u32)(((int)(mws << (30 - 2 * p))) >> 31);
                u32 w1u = __float_as_uint(w1) & m1;
                af.u[p] = __builtin_amdgcn_perm(w1u, w0u, 0x07060302u);  // bf16 truncate
            }
            const int jc = ks * 4 + quad;
#pragma unroll
            for (int ot = 0; ot < 4; ot++) {
                const int o = ot * 16 + m;
                short8 bfv = *(const short8*)(hB[cb] + (size_t)o * 64 + ((jc ^ (o & 7)) << 3));
                acc[ot] = __builtin_amdgcn_mfma_f32_16x16x32_bf16(af.v, bfv, acc[ot], 0, 0, 0);
            }
            accd = __builtin_amdgcn_mfma_f32_16x16x32_bf16(af.v, ones.v, accd, 0, 0, 0);
        }
        if (jt + 1 < T) {                  // stage next tile into the idle buffer
            const int nb = cb ^ 1;
            *(uint4*)(hB[nb] + (size_t)ow * 64 + ((cj ^ (ow & 7)) << 3)) = pf[0];
            *(uint4*)(hB[nb] + (size_t)(ow + 32) * 64 + ((cj ^ ((ow + 32) & 7)) << 3)) = pf[1];
        }
        __syncthreads();
    }
    // store bf16 partials (C/D layout: col=lane&15, row=quad*4+reg)
    u16* pb = part + (((size_t)(seg * 4 + b) * 4096) + rb * 64 + wave * 16) * 64;
#pragma unroll
    for (int ot = 0; ot < 4; ot++)
#pragma unroll
        for (int r = 0; r < 4; r++) {
            u32 v = __float_as_uint(acc[ot][r]) + 0x8000u;
            pb[(quad * 4 + r) * 64 + ot * 16 + m] = (u16)(v >> 16);
        }
    if (m == 0) {                          // accd cols all equal; rows quad*4+r
        float* lpb = lp + (size_t)(seg * 4 + b) * 4096 + rb * 64 + wave * 16 + quad * 4;
#pragma unroll
        for (int r = 0; r < 4; r++) lpb[r] = accd[r];
    }

    // ---- stream-K fixup: last segment-WG of (b,rb) combines + finishes ----
    __threadfence();                       // release this WG's stores (device)
    __syncthreads();                       // all threads fenced
    if (tid == 0) {
        u32 old = __hip_atomic_fetch_add(&cnt[b * 64 + rb], 1u,
                                         __ATOMIC_ACQ_REL, __HIP_MEMORY_SCOPE_AGENT);
        lastf = (old == S - 1) ? 1u : 0u;
    }
    __syncthreads();
    if (!lastf) return;
    __threadfence();                       // acquire for all lanes (inv L1)

    const int frow = tid >> 2, c16 = (tid & 3) << 4;   // 64 rows x 4 col-groups
    float sums[16];
#pragma unroll
    for (int i = 0; i < 16; i++) sums[i] = 0.f;
    float l = 0.f;
    for (int s = 0; s < S; s++) {
        const u16* pp = part + (((size_t)(s * 4 + b) * 4096) + rb * 64 + frow) * 64 + c16;
        uint4 q0 = *(const uint4*)pp;
        uint4 q1 = *(const uint4*)(pp + 8);
        const u32* q = (const u32*)&q0;
#pragma unroll
        for (int i = 0; i < 4; i++) {
            sums[2 * i] += __uint_as_float(q[i] << 16);
            sums[2 * i + 1] += __uint_as_float(q[i] & 0xffff0000u);
        }
        const u32* q2 = (const u32*)&q1;
#pragma unroll
        for (int i = 0; i < 4; i++) {
            sums[8 + 2 * i] += __uint_as_float(q2[i] << 16);
            sums[9 + 2 * i] += __uint_as_float(q2[i] & 0xffff0000u);
        }
        l += lp[(size_t)(s * 4 + b) * 4096 + rb * 64 + frow];
    }
    const float rl = 1.f / l;
    float* ob = out + ((size_t)(b * 4096 + rb * 64 + frow)) * 64 + c16;
#pragma unroll
    for (int v4 = 0; v4 < 4; v4++) {
        float4 o;
        float* ov = (float*)&o;
#pragma unroll
        for (int i = 0; i < 4; i++) {
            float p = sums[v4 * 4 + i] * rl;
            ov[i] = p > 0.f ? p : __builtin_amdgcn_exp2f(p * LOG2E) - 1.f;
        }
        *(float4*)(ob + v4 * 4) = o;
    }
}

// ---------------------------------------------------------------------------
extern "C" void kernel_launch(void* const* d_in, const int* in_sizes, int n_in,
                              void* d_out, int out_size, void* d_ws, size_t ws_size,
                              hipStream_t stream) {
    const float* x  = (const float*)d_in[0];
    const int* adj  = (const int*)d_in[1];
    const float* W  = (const float*)d_in[2];
    const float* a  = (const float*)d_in[3];
    float* out = (float*)d_out;
    char* ws = (char*)d_ws;

    // workspace layout
    u16* h_t   = (u16*)ws;                         // 2 MB
    u32* maskt = (u32*)(ws + (2 << 20));           // 2 MB
    float* s1p = (float*)(ws + (4 << 20));         // 64 KB
    float* s2p = s1p + 16384;                      // 64 KB
    u32* cnt   = (u32*)(s2p + 16384);              // 1 KB (zeroed by k0 block 0)
    float* lp  = (float*)(ws + (4u << 20) + 2 * 65536 + 1024);   // S*64 KB
    size_t base = (4u << 20) + 2 * 65536 + 1024;
    int S = 8;                                     // k2 j-split: 2048 WGs = 8 WG/CU
    while (S > 1 && base + (size_t)S * (65536 + 2097152) > ws_size) S >>= 1;
    u16* part = (u16*)(ws + base + (size_t)S * 65536);          // S*2 MB (bf16)

    k0<<<2304, 512, 0, stream>>>(adj, maskt, x, W, a, h_t, s1p, s2p, cnt);
    if (S == 8)
        k2_attn<16><<<dim3(64, 4, 8), 256, 0, stream>>>(h_t, maskt, s1p, s2p, part, lp, out, cnt);
    else if (S == 4)
        k2_attn<32><<<dim3(64, 4, 4), 256, 0, stream>>>(h_t, maskt, s1p, s2p, part, lp, out, cnt);
    else if (S == 2)
        k2_attn<64><<<dim3(64, 4, 2), 256, 0, stream>>>(h_t, maskt, s1p, s2p, part, lp, out, cnt);
    else
        k2_attn<128><<<dim3(64, 4, 1), 256, 0, stream>>>(h_t, maskt, s1p, s2p, part, lp, out, cnt);
}

// Round 13
// 162.766 us; speedup vs baseline: 2.9788x; 2.9788x over previous
//
#include <hip/hip_runtime.h>

#define LOG2E 1.4426950408889634f

typedef __attribute__((ext_vector_type(8))) short short8;
typedef __attribute__((ext_vector_type(4))) float f32x4;
using u32 = unsigned int;
using u16 = unsigned short;
using u64 = unsigned long long;

// ---------------------------------------------------------------------------
// Kernel 0: FUSED pack + k1f, roles INTERLEAVED (r12 put k1f at blocks 2048+
// which dispatch after all pack blocks -> no overlap; now bx%9==0 -> k1f so
// MFMA blocks are co-resident with the HBM-bound pack stream from t=0).
// NO device-scope fences/atomics anywhere (r12 lesson: per-WG agent fences =
// L2 writebacks on non-coherent-XCD gfx950 = 5x kernel-wide stall).
// ---------------------------------------------------------------------------
__global__ __launch_bounds__(512) void k0(const int* __restrict__ adj,
                                          u32* __restrict__ mask_t,
                                          const float* __restrict__ x,
                                          const float* __restrict__ W,
                                          const float* __restrict__ a,
                                          u16* __restrict__ h_t,
                                          float* __restrict__ s1p,
                                          float* __restrict__ s2p) {
    __shared__ u16 wtl[64 * 512];          // 64 KB; becomes red[] after K-loop
    const int tid = threadIdx.x;
    const int bx = blockIdx.x;

    if (bx % 9 != 0) {                     // ---------------- pack ----------------
        const int pidx = bx - 1 - bx / 9;  // 0..2047
        const int wid = (pidx * 512 + tid) >> 6;
        const int lane = tid & 63;
        for (int t = wid; t < 65536; t += 16384) {        // task = (row, 4-chunk grp)
            const int r = t >> 4, c4 = t & 15;
            const int* base = adj + (size_t)r * 4096 + c4 * 256 + lane;
            int v0 = __builtin_nontemporal_load(base);
            int v1 = __builtin_nontemporal_load(base + 64);
            int v2 = __builtin_nontemporal_load(base + 128);
            int v3 = __builtin_nontemporal_load(base + 192);
            u64 b0 = __ballot(v0 > 0);
            u64 b1 = __ballot(v1 > 0);
            u64 b2 = __ballot(v2 > 0);
            u64 b3 = __ballot(v3 > 0);
            if (lane < 8) {
                u64 bv = (lane & 4) ? ((lane & 2) ? b3 : b2) : ((lane & 2) ? b1 : b0);
                u32 w = (u32)(bv >> ((lane & 1) << 5));
                mask_t[(size_t)(c4 * 8 + lane) * 4096 + r] = w;
            }
        }
        return;
    }
    // ---------------- k1f ----------------
    const int kidx = bx / 9;               // 0..255: rt = kidx&63, b = kidx>>6
    const int rt = kidx & 63, b = kidx >> 6;
    {   // stage W (512x64 fp32) -> wtl[n][k] bf16, 16B-chunk XOR swizzle (n&7)
        const int kk = tid >> 4, n4 = (tid & 15) << 2;
#pragma unroll
        for (int it = 0; it < 16; it++) {
            int k = kk + it * 32;
            float4 w4 = *(const float4*)(W + (size_t)k * 64 + n4);
            const float* wf = (const float*)&w4;
            int kc = k >> 3, ko = k & 7;
#pragma unroll
            for (int i = 0; i < 4; i++) {
                int n = n4 + i;
                u32 v = __float_as_uint(wf[i]) + 0x8000u;       // round-half-up
                wtl[n * 512 + ((kc ^ (n & 7)) << 3) + ko] = (u16)(v >> 16);
            }
        }
    }
    __syncthreads();                       // wtl ready

    const int wave = tid >> 6, lane = tid & 63;
    const int g = wave & 3, kz = wave >> 2;
    const int m = lane & 15, quad = lane >> 4;
    const int row = rt * 64 + g * 16 + m;
    const float* xb = x + ((size_t)b * 4096 + row) * 512 + kz * 256 + quad * 8;

    f32x4 acc[4];
#pragma unroll
    for (int ot = 0; ot < 4; ot++) acc[ot] = (f32x4){0.f, 0.f, 0.f, 0.f};

    float4 ax[2][2];
#pragma unroll
    for (int s = 0; s < 2; s++) {          // preload A k-steps 0,1
        ax[s][0] = *(const float4*)(xb + s * 32);
        ax[s][1] = *(const float4*)(xb + s * 32 + 4);
    }
#pragma unroll
    for (int s = 0; s < 8; s++) {          // K=256 in 8 steps of 32
        const int cur = s & 1;
        union { u32 u[4]; short8 v; } af;
        const float* a0 = (const float*)&ax[cur][0];
#pragma unroll
        for (int p = 0; p < 4; p++) {      // round-half-up bf16 pack (lo=k even)
            u32 lo = __float_as_uint(a0[2 * p]) + 0x8000u;
            u32 hi = __float_as_uint(a0[2 * p + 1]) + 0x8000u;
            af.u[p] = __builtin_amdgcn_perm(hi, lo, 0x07060302u);
        }
#pragma unroll
        for (int ot = 0; ot < 4; ot++) {   // B direct from LDS (2-way = free)
            const int n = ot * 16 + m;
            const int chunk = kz * 32 + s * 4 + quad;
            short8 bv = *(const short8*)(wtl + n * 512 + ((chunk ^ (n & 7)) << 3));
            acc[ot] = __builtin_amdgcn_mfma_f32_16x16x32_bf16(af.v, bv, acc[ot], 0, 0, 0);
        }
        if (s + 2 < 8) {                   // A prefetch after consumption
            ax[cur][0] = *(const float4*)(xb + (s + 2) * 32);
            ax[cur][1] = *(const float4*)(xb + (s + 2) * 32 + 4);
        }
    }
    __syncthreads();                       // all wtl reads done -> reuse as red
    float* red = (float*)wtl;              // [4][16][64] fp32 = 16 KB
    if (kz) {
#pragma unroll
        for (int ot = 0; ot < 4; ot++)
#pragma unroll
            for (int r = 0; r < 4; r++)
                red[(g * 16 + quad * 4 + r) * 64 + ot * 16 + m] = acc[ot][r];
    }
    __syncthreads();
    if (kz) return;
#pragma unroll
    for (int ot = 0; ot < 4; ot++)
#pragma unroll
        for (int r = 0; r < 4; r++)
            acc[ot][r] += red[(g * 16 + quad * 4 + r) * 64 + ot * 16 + m];

    // epilogue: s1/s2 (pre-scaled by log2e) via shuffle reduce
    float a1v[4], a2v[4];
#pragma unroll
    for (int ot = 0; ot < 4; ot++) {
        a1v[ot] = a[ot * 16 + m];
        a2v[ot] = a[64 + ot * 16 + m];
    }
    float s1r[4], s2r[4];
#pragma unroll
    for (int r = 0; r < 4; r++) {
        s1r[r] = 0.f; s2r[r] = 0.f;
#pragma unroll
        for (int ot = 0; ot < 4; ot++) {
            s1r[r] = fmaf(acc[ot][r], a1v[ot], s1r[r]);
            s2r[r] = fmaf(acc[ot][r], a2v[ot], s2r[r]);
        }
    }
#pragma unroll
    for (int d = 1; d < 16; d <<= 1) {
#pragma unroll
        for (int r = 0; r < 4; r++) {
            s1r[r] += __shfl_xor(s1r[r], d);
            s2r[r] += __shfl_xor(s2r[r], d);
        }
    }
    if (m == 0) {
#pragma unroll
        for (int r = 0; r < 4; r++) {
            int rr = rt * 64 + g * 16 + quad * 4 + r;
            s1p[b * 4096 + rr] = s1r[r] * LOG2E;
            s2p[b * 4096 + rr] = s2r[r] * LOG2E;
        }
    }
    // h^T bf16 (round-half-up)
#pragma unroll
    for (int ot = 0; ot < 4; ot++) {
        u32 b0 = __float_as_uint(acc[ot][0]) + 0x8000u;
        u32 b1 = __float_as_uint(acc[ot][1]) + 0x8000u;
        u32 b2 = __float_as_uint(acc[ot][2]) + 0x8000u;
        u32 b3 = __float_as_uint(acc[ot][3]) + 0x8000u;
        uint2 u;
        u.x = (b0 >> 16) | (b1 & 0xffff0000u);
        u.y = (b2 >> 16) | (b3 & 0xffff0000u);
        *(uint2*)(h_t + ((size_t)(b * 64 + ot * 16 + m)) * 4096
                  + rt * 64 + g * 16 + quad * 4) = u;
    }
}

// ---------------------------------------------------------------------------
// Kernel 2: fused masked-softmax-numerator GEMM — r11-EXACT (160.4 us WIN
// config; r12's stream-K fixup reverted: no fences, no atomics).
// ---------------------------------------------------------------------------
template <int NSTEP>
__global__ __launch_bounds__(256, 8) void k2_attn(const u16* __restrict__ h_t,
                                                  const u32* __restrict__ mask_t,
                                                  const float* __restrict__ s1p,
                                                  const float* __restrict__ s2p,
                                                  u16* __restrict__ part,
                                                  float* __restrict__ lp) {
    constexpr int JSEG = NSTEP * 32;
    constexpr int T = NSTEP / 2;           // 64-j tiles
    __shared__ u16 hB[2][64 * 64];         // double buffer, xor-swizzled
    __shared__ float s2l[JSEG];
    const int b = blockIdx.y, seg = blockIdx.z, rb = blockIdx.x;
    const int tid = threadIdx.x, wave = tid >> 6, lane = tid & 63;
    const int m = lane & 15, quad = lane >> 4;
    const int row = rb * 64 + wave * 16 + m;
    const int jstart = seg * JSEG;
    const float t1 = s1p[b * 4096 + row];
    const u16* hsrc = h_t + (size_t)b * 64 * 4096 + jstart;
    const u32* mrow = mask_t + (size_t)(jstart >> 5) * 4096 + row;

    for (int t = tid; t < (JSEG >> 2); t += 256)
        ((float4*)s2l)[t] = ((const float4*)(s2p + b * 4096 + jstart))[t];

    f32x4 acc[4], accd;
#pragma unroll
    for (int ot = 0; ot < 4; ot++) acc[ot] = (f32x4){0.f, 0.f, 0.f, 0.f};
    accd = (f32x4){0.f, 0.f, 0.f, 0.f};

    u32 mw[4];
#pragma unroll
    for (int s = 0; s < 4; s++) mw[s] = mrow[(size_t)s * 4096];
    union { u32 u[4]; short8 v; } ones;
#pragma unroll
    for (int p = 0; p < 4; p++) ones.u[p] = 0x3F803F80u;   // bf16 1.0 pairs

    const int cj = tid & 7;                // 16B chunk column (8 j's)
    const int ow = tid >> 3;               // rows ow, ow+32
    uint4 pf[2];
    pf[0] = *(const uint4*)(hsrc + (size_t)ow * 4096 + (cj << 3));
    pf[1] = *(const uint4*)(hsrc + (size_t)(ow + 32) * 4096 + (cj << 3));
    *(uint4*)(hB[0] + (size_t)ow * 64 + ((cj ^ (ow & 7)) << 3)) = pf[0];
    *(uint4*)(hB[0] + (size_t)(ow + 32) * 64 + ((cj ^ ((ow + 32) & 7)) << 3)) = pf[1];
    __syncthreads();                       // tile 0 + s2l ready

    for (int jt = 0; jt < T; jt++) {
        const int cb = jt & 1;
        if (jt + 1 < T) {                  // global prefetch of next 64-j tile
            pf[0] = *(const uint4*)(hsrc + (size_t)ow * 4096 + (jt + 1) * 64 + (cj << 3));
            pf[1] = *(const uint4*)(hsrc + (size_t)(ow + 32) * 4096 + (jt + 1) * 64 + (cj << 3));
        }
#pragma unroll
        for (int ks = 0; ks < 2; ks++) {
            const int s = jt * 2 + ks;
            // consume BEFORE the distance-4 prefetch overwrites the slot
            const u32 mws = mw[s & 3] >> (quad * 8);
            if (s + 4 < NSTEP) mw[(s + 4) & 3] = mrow[(size_t)(s + 4) * 4096];

            const float4 sa = *(const float4*)&s2l[s * 32 + quad * 8];
            const float4 sb = *(const float4*)&s2l[s * 32 + quad * 8 + 4];
            const float sv[8] = {sa.x, sa.y, sa.z, sa.w, sb.x, sb.y, sb.z, sb.w};
            union { u32 u[4]; short8 v; } af;
#pragma unroll
            for (int p = 0; p < 4; p++) {
                float t0 = t1 + sv[2 * p];
                float u0 = fmaxf(t0, 0.2f * t0);                     // leaky-relu (log2 dom)
                float w0 = __builtin_amdgcn_exp2f(u0);
                u32 m0 = (u32)(((int)(mws << (31 - 2 * p))) >> 31);  // bit -> all-ones/0
                u32 w0u = __float_as_uint(w0) & m0;                  // masked -> +0.0
                float t2 = t1 + sv[2 * p + 1];
                float u2 = fmaxf(t2, 0.2f * t2);
                float w1 = __builtin_amdgcn_exp2f(u2);
                u32 m1 = (u32)(((int)(mws << (30 - 2 * p))) >> 31);
                u32 w1u = __float_as_uint(w1) & m1;
                af.u[p] = __builtin_amdgcn_perm(w1u, w0u, 0x07060302u);  // bf16 truncate
            }
            const int jc = ks * 4 + quad;
#pragma unroll
            for (int ot = 0; ot < 4; ot++) {
                const int o = ot * 16 + m;
                short8 bfv = *(const short8*)(hB[cb] + (size_t)o * 64 + ((jc ^ (o & 7)) << 3));
                acc[ot] = __builtin_amdgcn_mfma_f32_16x16x32_bf16(af.v, bfv, acc[ot], 0, 0, 0);
            }
            accd = __builtin_amdgcn_mfma_f32_16x16x32_bf16(af.v, ones.v, accd, 0, 0, 0);
        }
        if (jt + 1 < T) {                  // stage next tile into the idle buffer
            const int nb = cb ^ 1;
            *(uint4*)(hB[nb] + (size_t)ow * 64 + ((cj ^ (ow & 7)) << 3)) = pf[0];
            *(uint4*)(hB[nb] + (size_t)(ow + 32) * 64 + ((cj ^ ((ow + 32) & 7)) << 3)) = pf[1];
        }
        __syncthreads();
    }
    // C/D layout: col=lane&15, row=quad*4+reg; partials stored bf16
    u16* pb = part + (((size_t)(seg * 4 + b) * 4096) + rb * 64 + wave * 16) * 64;
#pragma unroll
    for (int ot = 0; ot < 4; ot++)
#pragma unroll
        for (int r = 0; r < 4; r++) {
            u32 v = __float_as_uint(acc[ot][r]) + 0x8000u;
            pb[(quad * 4 + r) * 64 + ot * 16 + m] = (u16)(v >> 16);
        }
    if (m == 0) {                          // accd cols all equal; rows quad*4+r
        float* lpb = lp + (size_t)(seg * 4 + b) * 4096 + rb * 64 + wave * 16 + quad * 4;
#pragma unroll
        for (int r = 0; r < 4; r++) lpb[r] = accd[r];
    }
}

// ---------------------------------------------------------------------------
// Kernel 3: combine j-split bf16 partials, normalize, elu (r11-exact).
// ---------------------------------------------------------------------------
template <int S>
__global__ __launch_bounds__(256) void k3_fin(const u16* __restrict__ part,
                                              const float* __restrict__ lp,
                                              float* __restrict__ out) {
    int idx = blockIdx.x * 256 + threadIdx.x;    // 262144 = 4*4096*16
    int o4 = (idx & 15) << 2;
    int bi = idx >> 4;
    uint2 pv[S];
    float lv[S];
#pragma unroll
    for (int s = 0; s < S; s++) {
        pv[s] = *(const uint2*)&part[((size_t)s * 16384 + bi) * 64 + o4];
        lv[s] = lp[(size_t)s * 16384 + bi];
    }
    float p0 = 0.f, p1 = 0.f, p2 = 0.f, p3 = 0.f, l = 0.f;
#pragma unroll
    for (int s = 0; s < S; s++) {
        p0 += __uint_as_float(pv[s].x << 16);
        p1 += __uint_as_float(pv[s].x & 0xffff0000u);
        p2 += __uint_as_float(pv[s].y << 16);
        p3 += __uint_as_float(pv[s].y & 0xffff0000u);
        l += lv[s];
    }
    float rl = 1.f / l;
    p0 *= rl; p1 *= rl; p2 *= rl; p3 *= rl;
    float4 o;
    o.x = p0 > 0.f ? p0 : __builtin_amdgcn_exp2f(p0 * LOG2E) - 1.f;
    o.y = p1 > 0.f ? p1 : __builtin_amdgcn_exp2f(p1 * LOG2E) - 1.f;
    o.z = p2 > 0.f ? p2 : __builtin_amdgcn_exp2f(p2 * LOG2E) - 1.f;
    o.w = p3 > 0.f ? p3 : __builtin_amdgcn_exp2f(p3 * LOG2E) - 1.f;
    *(float4*)&out[(size_t)bi * 64 + o4] = o;
}

// ---------------------------------------------------------------------------
extern "C" void kernel_launch(void* const* d_in, const int* in_sizes, int n_in,
                              void* d_out, int out_size, void* d_ws, size_t ws_size,
                              hipStream_t stream) {
    const float* x  = (const float*)d_in[0];
    const int* adj  = (const int*)d_in[1];
    const float* W  = (const float*)d_in[2];
    const float* a  = (const float*)d_in[3];
    float* out = (float*)d_out;
    char* ws = (char*)d_ws;

    // workspace layout
    u16* h_t   = (u16*)ws;                         // 2 MB
    u32* maskt = (u32*)(ws + (2 << 20));           // 2 MB
    float* s1p = (float*)(ws + (4 << 20));         // 64 KB
    float* s2p = s1p + 16384;                      // 64 KB
    float* lp  = s2p + 16384;                      // S*64 KB (1 float/row)
    size_t base = (4u << 20) + 2 * 65536;
    int S = 8;                                     // k2 j-split: 2048 WGs = 8 WG/CU
    while (S > 1 && base + (size_t)S * (65536 + 2097152) > ws_size) S >>= 1;
    u16* part = (u16*)(ws + base + (size_t)S * 65536);        // S*2 MB (bf16)

    k0<<<2304, 512, 0, stream>>>(adj, maskt, x, W, a, h_t, s1p, s2p);
    if (S == 8)      k2_attn<16><<<dim3(64, 4, 8), 256, 0, stream>>>(h_t, maskt, s1p, s2p, part, lp);
    else if (S == 4) k2_attn<32><<<dim3(64, 4, 4), 256, 0, stream>>>(h_t, maskt, s1p, s2p, part, lp);
    else if (S == 2) k2_attn<64><<<dim3(64, 4, 2), 256, 0, stream>>>(h_t, maskt, s1p, s2p, part, lp);
    else             k2_attn<128><<<dim3(64, 4, 1), 256, 0, stream>>>(h_t, maskt, s1p, s2p, part, lp);
    if (S == 8)      k3_fin<8><<<1024, 256, 0, stream>>>(part, lp, out);
    else if (S == 4) k3_fin<4><<<1024, 256, 0, stream>>>(part, lp, out);
    else if (S == 2) k3_fin<2><<<1024, 256, 0, stream>>>(part, lp, out);
    else             k3_fin<1><<<1024, 256, 0, stream>>>(part, lp, out);
}